// Round 8
// baseline (220.737 us; speedup 1.0000x reference)
//
#include <hip/hip_runtime.h>
#include <hip/hip_bf16.h>

// SelfAttention: B=8, N=2048, D=512, fp32 in/out.
// No-max softmax: P = exp(S)*mask, l = rowsum(P), O = (P.V)/l.
// Pipeline: convert_all (+lde zero) -> qkv_gemm -> gemm_s -> gemm_o.
// r11 lesson: the deep phase template needs a LONG K-loop (gemm_o NT=32 +ve; gemm_s
// NT=8 -> fill 25%, 1 blk/CU, REGRESSED 46->57us). For K=512 kernels, multi-block
// overlap beats intra-block pipelining.
// r12: gemm_s & qkv = 2-barrier loop (r6-proven sync) at 256x128 tiles, 8 waves,
// single 48KB LDS -> 3 blk/CU (24 waves/CU): +33% staging efficiency (256 MFMA/48KB
// vs 128/32KB), half the blocks, higher occupancy. Epilogue transposes run in two
// 32KB passes (wave owns pass wm>>1; exp/lpart computed once). gemm_o keeps the r9
// phase schedule (BM=256xBN=128, 2-deep LDS, counted vmcnt(6), NT=32).
// ws (ushort elems): Pm[8*2048*2048] (Xb aliases head) | Wb[1536*512] | Qb | Kb
//   | Vtb[8*512*2048] | lde[16384 f32]  ~= 113.6 MB.

typedef __attribute__((ext_vector_type(8))) short short8;   // 8 x bf16
typedef __attribute__((ext_vector_type(4))) float f32x4;    // MFMA 16x16 acc

#define DEV __device__ __forceinline__
#define GLOBAL_AS __attribute__((address_space(1)))
#define LDS_AS __attribute__((address_space(3)))

static DEV ushort f2bs(float f) {  // fp32 -> bf16 bits, RNE
  union { float f; unsigned u; } x; x.f = f;
  unsigned r = (x.u + 0x7fffu + ((x.u >> 16) & 1u)) >> 16;
  return (ushort)r;
}

static DEV f32x4 mfma16(short8 a, short8 b, f32x4 c) {
  // C[m][n] += sum_k A[m][k]*B[n][k]
  return __builtin_amdgcn_mfma_f32_16x16x32_bf16(a, b, c, 0, 0, 0);
}

static DEV void async16(const void* g, void* l) {
  __builtin_amdgcn_global_load_lds((const GLOBAL_AS void*)g, (LDS_AS void*)l, 16, 0, 0);
}

// ---------------------------------------------------------------------------
// fp32->bf16 converts (weights, X) + lde zeroing, one kernel.
__global__ void convert_all(const float* __restrict__ wq, const float* __restrict__ wk,
                            const float* __restrict__ wv, const float* __restrict__ x,
                            ushort* __restrict__ wb, ushort* __restrict__ xb,
                            float* __restrict__ lde) {
  int i = blockIdx.x * 256 + threadIdx.x;
  if (i >= 2293760) {                       // lde tail: 4096 float4 groups
    int off = (i - 2293760) * 4;
    float4 z; z.x = 0.f; z.y = 0.f; z.z = 0.f; z.w = 0.f;
    *(float4*)(lde + off) = z;
    return;
  }
  const float* src;
  ushort* dst;
  if (i < 196608) {
    int which = i >> 16;
    int off = (i & 65535) * 4;
    src = ((which == 0) ? wq : (which == 1) ? wk : wv) + off;
    dst = wb + (size_t)which * 262144 + off;
  } else {
    int off = (i - 196608) * 4;
    src = x + off;
    dst = xb + off;
  }
  float4 v = *(const float4*)src;
  ushort4 o;
  o.x = f2bs(v.x); o.y = f2bs(v.y); o.z = f2bs(v.z); o.w = f2bs(v.w);
  *(ushort4*)dst = o;
}

// ===========================================================================
// Common staging (8 waves, 256x64 A-tile, 128x64 B-tile; rows 128B = 8 chunks of
// 16B; LDS chunk c holds global chunk c^(row&7)). One instr = 8 rows per wave.
// Scope requirements: gA,gB,glda,gldb,arow0,brow0,SdA,SdB,wave,lane.
#define ST_A1(kt, rd)                                                          \
  do {                                                                         \
    int rowbase_ = (rd) * 64 + wave * 8;                                       \
    int r_ = rowbase_ + (lane >> 3);                                           \
    int gc_ = (lane & 7) ^ (r_ & 7);                                           \
    async16(gA + (size_t)(arow0 + r_) * glda + (kt) * 64 + gc_ * 8,            \
            SdA + rowbase_ * 64);                                              \
  } while (0)

#define ST_B1(kt, rd)                                                          \
  do {                                                                         \
    int rowbase_ = (rd) * 64 + wave * 8;                                       \
    int r_ = rowbase_ + (lane >> 3);                                           \
    int gc_ = (lane & 7) ^ (r_ & 7);                                           \
    async16(gB + (size_t)(brow0 + r_) * gldb + (kt) * 64 + gc_ * 8,            \
            SdB + rowbase_ * 64);                                              \
  } while (0)

// 2-barrier K-step (r6-proven sync): sync -> stage 6 async16 -> sync(vmcnt drain
// by compiler) -> 2 kslices x 16 MFMA. Per-wave 64x64 output acc[4][4];
// wm = wave>>1 (A span), wn = wave&1 (B span).
#define SIMPLE_STEP(kt)                                                        \
  do {                                                                         \
    __syncthreads();                                                           \
    ST_A1(kt, 0); ST_A1(kt, 1); ST_A1(kt, 2); ST_A1(kt, 3);                    \
    ST_B1(kt, 0); ST_B1(kt, 1);                                                \
    __syncthreads();                                                           \
    _Pragma("unroll")                                                          \
    for (int ks = 0; ks < 2; ks++) {                                           \
      short8 af[4], bf[4];                                                     \
      _Pragma("unroll")                                                        \
      for (int mf = 0; mf < 4; mf++) {                                         \
        int ra = wm * 64 + mf * 16 + c16;                                      \
        af[mf] = *(const short8*)&SdA[ra * 64 + (((ks * 4 + quad) ^ (ra & 7)) * 8)]; \
      }                                                                        \
      _Pragma("unroll")                                                        \
      for (int nf = 0; nf < 4; nf++) {                                         \
        int rb = wn * 64 + nf * 16 + c16;                                      \
        bf[nf] = *(const short8*)&SdB[rb * 64 + (((ks * 4 + quad) ^ (rb & 7)) * 8)]; \
      }                                                                        \
      _Pragma("unroll")                                                        \
      for (int mf = 0; mf < 4; mf++)                                           \
        _Pragma("unroll")                                                      \
        for (int nf = 0; nf < 4; nf++)                                         \
          acc[mf][nf] = mfma16(af[mf], bf[nf], acc[mf][nf]);                   \
    }                                                                          \
  } while (0)

// ---------------------------------------------------------------------------
// qkv_gemm: C[n][eg] = sum_d X[n][d]*W[eg][d] + bias. 256x128 tiles, grid (64,12):
// rowblk = 256 token rows; colblk: 0-3 Q (scaled), 4-7 K, 8-11 V^T.
__launch_bounds__(512, 4)
__global__ void qkv_gemm(const ushort* __restrict__ Xb, const ushort* __restrict__ Wb,
                         const float* __restrict__ bq, const float* __restrict__ bk,
                         const float* __restrict__ bv,
                         ushort* __restrict__ Qb, ushort* __restrict__ Kb,
                         ushort* __restrict__ Vtb) {
  const int rowblk = blockIdx.x;      // 0..63 (token rows / 256)
  const int colblk = blockIdx.y;      // 0..11 (output cols / 128)
  const int z = colblk >> 2;          // 0 Q, 1 K, 2 V

  extern __shared__ ushort Sd[];      // 48 KB
  ushort* SdA = Sd;                   // [256*64]
  ushort* SdB = Sd + 16384;           // [128*64]

  const int tid = threadIdx.x;
  const int wave = tid >> 6, lane = tid & 63, quad = lane >> 4, c16 = lane & 15;
  const int wm = wave >> 1, wn = wave & 1;   // 4M x 2N; per-wave 64n x 64eg

  const ushort* gA = Xb;  const int glda = 512; const int arow0 = rowblk * 256;
  const ushort* gB = Wb;  const int gldb = 512; const int brow0 = colblk * 128;

  f32x4 acc[4][4];
#pragma unroll
  for (int mf = 0; mf < 4; mf++)
#pragma unroll
    for (int nf = 0; nf < 4; nf++) acc[mf][nf] = (f32x4)0.0f;

  for (int kt = 0; kt < 8; kt++) SIMPLE_STEP(kt);

  const float* bias = (z == 0) ? bq : (z == 1) ? bk : bv;
  const int col0 = (colblk & 3) * 128 + wn * 64;     // el base 0..511
  float bvals[4];
#pragma unroll
  for (int nf = 0; nf < 4; nf++) bvals[nf] = bias[col0 + nf * 16 + c16];
  const float sc = (z == 0) ? 0.044194173824159216f : 1.0f;   // 1/sqrt(512) into Q

  const int row0 = rowblk * 256 + wm * 64;
  if (z < 2) {
    ushort* O = (z == 0) ? Qb : Kb;
#pragma unroll
    for (int mf = 0; mf < 4; mf++)
#pragma unroll
      for (int nf = 0; nf < 4; nf++) {
        int el = col0 + nf * 16 + c16;
#pragma unroll
        for (int r = 0; r < 4; r++) {
          int n = row0 + mf * 16 + quad * 4 + r;
          O[(size_t)n * 512 + el] = f2bs((acc[mf][nf][r] + bvals[nf]) * sc);
        }
      }
  } else {
    // V^T via two 32KB LDS transpose passes (pass = wm>>1 over the 256-n span),
    // then 64-B sector-complete streaming stores.
    ushort* T = Sd;                    // T_half[el 0..127][n 0..127], 16-chunk rows
    const int bb = rowblk >> 3;
    const int nbase = (rowblk & 7) * 256;
    const int elbase = (colblk & 3) * 128;
    const int c4 = tid & 3, er = tid >> 2;
    __syncthreads();                   // K-loop LDS reads done
#pragma unroll
    for (int pass = 0; pass < 2; pass++) {
      if ((wm >> 1) == pass) {
#pragma unroll
        for (int nf = 0; nf < 4; nf++) {
          int ell = wn * 64 + nf * 16 + c16;         // local el 0..127
#pragma unroll
          for (int mf = 0; mf < 4; mf++) {
            int n0p = (wm & 1) * 64 + mf * 16 + quad * 4;  // n within pass 0..127
            ushort4 o;
            o.x = f2bs(acc[mf][nf][0] + bvals[nf]);
            o.y = f2bs(acc[mf][nf][1] + bvals[nf]);
            o.z = f2bs(acc[mf][nf][2] + bvals[nf]);
            o.w = f2bs(acc[mf][nf][3] + bvals[nf]);
            *(ushort4*)&T[ell * 128 + (((n0p >> 3) ^ (ell & 15)) << 3) + (n0p & 4)] = o;
          }
        }
      }
      __syncthreads();
      size_t ge = ((size_t)bb * 512 + elbase + er) * 2048;
#pragma unroll
      for (int j = 0; j < 4; j++) {
        int ch = j * 4 + c4;                         // 16B chunk 0..15
        short8 v = *(short8*)&T[er * 128 + ((ch ^ (er & 15)) << 3)];
        *(short8*)(Vtb + ge + nbase + pass * 128 + ch * 8) = v;
      }
      __syncthreads();
    }
  }
}

// ---------------------------------------------------------------------------
// gemm_s: per batch C[m=key][n=query] = K.Q^T (Q pre-scaled). 256key x 128query
// tiles, grid (8,16,8). Epilogue: exp*mask -> two 32KB LDS transpose passes ->
// P[b][query][key] 64-B runs; l[b][query] += partials (atomics into zeroed lde).
__launch_bounds__(512, 4)
__global__ void gemm_s(const ushort* __restrict__ Kb, const ushort* __restrict__ Qb,
                       const int* __restrict__ mask, ushort* __restrict__ Pm,
                       float* __restrict__ l) {
  const int b = blockIdx.z;
  const int rowblk = blockIdx.x;   // key tile 0..7 (256 keys)
  const int colblk = blockIdx.y;   // query tile 0..15 (128 queries)

  extern __shared__ ushort Sd[];   // 48 KB
  ushort* SdA = Sd;
  ushort* SdB = Sd + 16384;

  const int tid = threadIdx.x;
  const int wave = tid >> 6, lane = tid & 63, quad = lane >> 4, c16 = lane & 15;
  const int wm = wave >> 1, wn = wave & 1;   // 4M(key) x 2N(query)

  const ushort* gA = Kb + (size_t)b * 2048 * 512;  const int glda = 512;
  const int arow0 = rowblk * 256;
  const ushort* gB = Qb + (size_t)b * 2048 * 512;  const int gldb = 512;
  const int brow0 = colblk * 128;

  f32x4 acc[4][4];
#pragma unroll
  for (int mf = 0; mf < 4; mf++)
#pragma unroll
    for (int nf = 0; nf < 4; nf++) acc[mf][nf] = (f32x4)0.0f;

  for (int kt = 0; kt < 8; kt++) SIMPLE_STEP(kt);

  // Epilogue: per-pass exp + transpose write (wave owns pass wm>>1; exp once).
  float lpart[4] = {0.0f, 0.0f, 0.0f, 0.0f};
  ushort* T = Sd;                  // T_half[q 0..127][key 0..127], 16-chunk rows
  const int c4 = tid & 3, er = tid >> 2;
  __syncthreads();                 // K-loop LDS reads done
#pragma unroll
  for (int pass = 0; pass < 2; pass++) {
    if ((wm >> 1) == pass) {
#pragma unroll
      for (int mf = 0; mf < 4; mf++) {
        int k0p = (wm & 1) * 64 + mf * 16 + quad * 4;     // key within pass 0..127
        int keyg = rowblk * 256 + pass * 128 + k0p;       // global key in batch
        int4 mv = *(const int4*)&mask[b * 2048 + keyg];
        float m0 = mv.x ? 1.0f : 0.0f, m1 = mv.y ? 1.0f : 0.0f;
        float m2 = mv.z ? 1.0f : 0.0f, m3 = mv.w ? 1.0f : 0.0f;
#pragma unroll
        for (int nf = 0; nf < 4; nf++) {
          int ql = wn * 64 + nf * 16 + c16;               // local query 0..127
          float p0 = __expf(acc[mf][nf][0]) * m0;
          float p1 = __expf(acc[mf][nf][1]) * m1;
          float p2 = __expf(acc[mf][nf][2]) * m2;
          float p3 = __expf(acc[mf][nf][3]) * m3;
          ushort4 o;
          o.x = f2bs(p0); o.y = f2bs(p1); o.z = f2bs(p2); o.w = f2bs(p3);
          *(ushort4*)&T[ql * 128 + (((k0p >> 3) ^ (ql & 15)) << 3) + (k0p & 4)] = o;
          lpart[nf] += p0 + p1 + p2 + p3;
        }
      }
    }
    __syncthreads();
    size_t gq = ((size_t)b * 2048 + colblk * 128 + er) * 2048;
#pragma unroll
    for (int j = 0; j < 4; j++) {
      int ch = j * 4 + c4;                                // 16B chunk 0..15
      short8 v = *(short8*)&T[er * 128 + ((ch ^ (er & 15)) << 3)];
      *(short8*)(Pm + gq + rowblk * 256 + pass * 128 + ch * 8) = v;
    }
    __syncthreads();
  }
#pragma unroll
  for (int nf = 0; nf < 4; nf++) {
    float v = lpart[nf];
    v += __shfl_xor(v, 16, 64);
    v += __shfl_xor(v, 32, 64);
    if (quad == 0)
      atomicAdd(&l[b * 2048 + colblk * 128 + wn * 64 + nf * 16 + c16], v);
  }
}

// ===========================================================================
// gemm_o phase machinery (r9-proven): BM=256 x BN=128, 8 waves, 96KB 2-deep LDS,
// per-tile fine phases + ONE counted vmcnt(6) per K-tile.
#define PH_ST_A(pp, kt, rd)                                                    \
  do {                                                                         \
    int rowbase_ = (rd) * 64 + wave * 8;                                       \
    int r_ = rowbase_ + (lane >> 3);                                           \
    int gc_ = (lane & 7) ^ (r_ & 7);                                           \
    async16(gA + (size_t)(arow0 + r_) * glda + (kt) * 64 + gc_ * 8,            \
            SdA + (pp) * 16384 + rowbase_ * 64);                               \
  } while (0)

#define PH_ST_B(pp, kt, rd)                                                    \
  do {                                                                         \
    int rowbase_ = (rd) * 64 + wave * 8;                                       \
    int r_ = rowbase_ + (lane >> 3);                                           \
    int gc_ = (lane & 7) ^ (r_ & 7);                                           \
    async16(gB + (size_t)(brow0 + r_) * gldb + (kt) * 64 + gc_ * 8,            \
            SdB + (pp) * 8192 + rowbase_ * 64);                                \
  } while (0)

#define PH_READ(pp, ks, afx, bfx)                                              \
  do {                                                                         \
    const ushort* Ap_ = SdA + (pp) * 16384;                                    \
    const ushort* Bp_ = SdB + (pp) * 8192;                                     \
    _Pragma("unroll")                                                          \
    for (int mf = 0; mf < 4; mf++) {                                           \
      int ra = wm * 64 + mf * 16 + c16;                                        \
      afx[mf] = *(const short8*)&Ap_[ra * 64 + ((((ks)*4 + quad) ^ (ra & 7)) * 8)]; \
    }                                                                          \
    _Pragma("unroll")                                                          \
    for (int nf = 0; nf < 4; nf++) {                                           \
      int rb = wn * 64 + nf * 16 + c16;                                        \
      bfx[nf] = *(const short8*)&Bp_[rb * 64 + ((((ks)*4 + quad) ^ (rb & 7)) * 8)]; \
    }                                                                          \
  } while (0)

#define PH_MFMA(afx, bfx, h)                                                   \
  do {                                                                         \
    __builtin_amdgcn_s_setprio(1);                                             \
    _Pragma("unroll")                                                          \
    for (int mf = (h) * 2; mf < (h) * 2 + 2; mf++)                             \
      _Pragma("unroll")                                                        \
      for (int nf = 0; nf < 4; nf++)                                           \
        acc[mf][nf] = mfma16(afx[mf], bfx[nf], acc[mf][nf]);                   \
    __builtin_amdgcn_s_setprio(0);                                             \
  } while (0)

#define PH_TILE(pp, kt, dostage)                                               \
  do {                                                                         \
    PH_READ(pp, 0, af0, bf0);                                                  \
    __builtin_amdgcn_s_barrier();                                              \
    asm volatile("s_waitcnt lgkmcnt(0)" ::: "memory");                         \
    __builtin_amdgcn_sched_barrier(0);                                         \
    PH_MFMA(af0, bf0, 0);                                                      \
    __builtin_amdgcn_s_barrier();                                              \
    PH_READ(pp, 1, af1, bf1);                                                  \
    __builtin_amdgcn_s_barrier();                                              \
    asm volatile("s_waitcnt lgkmcnt(0)" ::: "memory");                         \
    __builtin_amdgcn_sched_barrier(0);                                         \
    PH_MFMA(af0, bf0, 1);                                                      \
    __builtin_amdgcn_s_barrier();   /* all waves' buf-pp reads retired */      \
    if (dostage) { PH_ST_A(pp, (kt) + 2, 0); PH_ST_A(pp, (kt) + 2, 1);         \
                   PH_ST_A(pp, (kt) + 2, 2); }                                 \
    PH_MFMA(af1, bf1, 0);                                                      \
    __builtin_amdgcn_s_barrier();                                              \
    if (dostage) { PH_ST_A(pp, (kt) + 2, 3); PH_ST_B(pp, (kt) + 2, 0);         \
                   PH_ST_B(pp, (kt) + 2, 1); }                                 \
    PH_MFMA(af1, bf1, 1);                                                      \
    if (dostage) { asm volatile("s_waitcnt vmcnt(6)" ::: "memory"); }          \
    else         { asm volatile("s_waitcnt vmcnt(0)" ::: "memory"); }          \
    __builtin_amdgcn_sched_barrier(0);                                         \
    __builtin_amdgcn_s_barrier();   /* next tile resident for all waves */     \
  } while (0)

#define PH_PROLOGUE()                                                          \
  do {                                                                         \
    PH_ST_A(0, 0, 0); PH_ST_A(0, 0, 1); PH_ST_A(0, 0, 2); PH_ST_A(0, 0, 3);    \
    PH_ST_B(0, 0, 0); PH_ST_B(0, 0, 1);                                        \
    PH_ST_A(1, 1, 0); PH_ST_A(1, 1, 1); PH_ST_A(1, 1, 2); PH_ST_A(1, 1, 3);    \
    PH_ST_B(1, 1, 0); PH_ST_B(1, 1, 1);                                        \
    asm volatile("s_waitcnt vmcnt(6)" ::: "memory");                           \
    __builtin_amdgcn_sched_barrier(0);                                         \
    __builtin_amdgcn_s_barrier();                                              \
  } while (0)

// gemm_o, phase-scheduled (r9): per batch C[m=query][n=d] = P . V^T; /l, fp32 out.
__launch_bounds__(512, 2)
__global__ void gemm_o(const ushort* __restrict__ Pm, const ushort* __restrict__ Vtb,
                       const float* __restrict__ l, float* __restrict__ out) {
  const int bid = blockIdx.x;
  const int b = bid & 7;             // batch -> XCD pin
  const int rowblk = (bid >> 3) & 7; // query tile 0..7 (256 rows)
  const int colblk = bid >> 6;       // d tile 0..3 (128 cols)

  extern __shared__ ushort Sd[];     // 96 KB
  ushort* SdA = Sd;
  ushort* SdB = Sd + 32768;

  const int tid = threadIdx.x;
  const int wave = tid >> 6, lane = tid & 63, quad = lane >> 4, c16 = lane & 15;
  const int wm = wave >> 1, wn = wave & 1;   // 4M x 2N; per-wave 64q x 64d

  const ushort* gA = Pm + (size_t)b * 2048 * 2048;  const int glda = 2048;
  const int arow0 = rowblk * 256;
  const ushort* gB = Vtb + (size_t)b * 512 * 2048;  const int gldb = 2048;
  const int brow0 = colblk * 128;

  f32x4 acc[4][4];
#pragma unroll
  for (int mf = 0; mf < 4; mf++)
#pragma unroll
    for (int nf = 0; nf < 4; nf++) acc[mf][nf] = (f32x4)0.0f;

  PH_PROLOGUE();
  short8 af0[4], bf0[4], af1[4], bf1[4];
  for (int i = 0; i < 16; i++) {
    const int ds = (i < 15);
    PH_TILE(0, 2 * i, ds);
    PH_TILE(1, 2 * i + 1, ds);
  }

  // Epilogue: /l, fp32 out.
  const int row0 = rowblk * 256 + wm * 64;   // query
  const int col0 = colblk * 128 + wn * 64;   // d
  float linv[4][4];
#pragma unroll
  for (int mf = 0; mf < 4; mf++)
#pragma unroll
    for (int r = 0; r < 4; r++)
      linv[mf][r] = 1.0f / l[b * 2048 + row0 + mf * 16 + quad * 4 + r];
#pragma unroll
  for (int mf = 0; mf < 4; mf++)
#pragma unroll
    for (int nf = 0; nf < 4; nf++) {
      int col = col0 + nf * 16 + c16;
#pragma unroll
      for (int r = 0; r < 4; r++) {
        int row = row0 + mf * 16 + quad * 4 + r;
        out[((size_t)b * 2048 + row) * 512 + col] = acc[mf][nf][r] * linv[mf][r];
      }
    }
}

// ---------------------------------------------------------------------------
extern "C" void kernel_launch(void* const* d_in, const int* in_sizes, int n_in,
                              void* d_out, int out_size, void* d_ws, size_t ws_size,
                              hipStream_t stream) {
  (void)in_sizes; (void)n_in; (void)out_size; (void)ws_size;
  const float* X    = (const float*)d_in[0];
  const int*   mask = (const int*)d_in[1];
  const float* Wk   = (const float*)d_in[2];
  const float* bk   = (const float*)d_in[3];
  const float* Wq   = (const float*)d_in[4];
  const float* bq   = (const float*)d_in[5];
  const float* Wv   = (const float*)d_in[6];
  const float* bv   = (const float*)d_in[7];
  float* out = (float*)d_out;

  ushort* ws  = (ushort*)d_ws;
  ushort* Pm  = ws;                             // [8][2048][2048] bf16 (64 MB)
  ushort* Xb  = ws;                             // [16384][512] aliases Pm (dead after qkv)
  ushort* Wb  = ws + (size_t)33554432;          // [1536][512]  rows = [Wq;Wk;Wv]
  ushort* Qb  = Wb + (size_t)786432;            // [16384][512] pre-scaled
  ushort* Kb  = Qb + (size_t)8388608;           // [16384][512]
  ushort* Vtb = Kb + (size_t)8388608;           // [8][512][2048]
  float*  lde = (float*)(Vtb + (size_t)8388608);// [16384] softmax denominators

  convert_all<<<8976, 256, 0, stream>>>(Wq, Wk, Wv, X, Wb, Xb, lde);
  qkv_gemm<<<dim3(64, 12), 512, 49152, stream>>>(Xb, Wb, bq, bk, bv, Qb, Kb, Vtb);
  gemm_s<<<dim3(8, 16, 8), 512, 49152, stream>>>(Kb, Qb, mask, Pm, lde);
  gemm_o<<<256, 512, 98304, stream>>>(Pm, Vtb, lde, out);
}

// Round 9
// 197.351 us; speedup vs baseline: 1.1185x; 1.1185x over previous
//
#include <hip/hip_runtime.h>
#include <hip/hip_bf16.h>

// SelfAttention: B=8, N=2048, D=512, fp32 in/out.
// No-max softmax: P = exp(S)*mask, l = rowsum(P), O = (P.V)/l.
// Pipeline: convert_all (+lde zero) -> qkv_gemm -> gemm_s -> gemm_o.
// CONFIG = r9 (best measured 204.7us) + gemm_s XCD batch-pinning.
// Settled lessons: r7 full fusion = barrier-bound (-46us). r8/r12 tile growth on the
// 2-barrier form REGRESSES (write-amp + occupancy loss). r11: deep phase pipeline
// needs LONG K (gemm_o NT=32 ok; K=512 NT=8 regresses). r6 form (128^2, BK=64,
// 256thr, occ4) is the K=512 local optimum — do not resize it.
// r13 tweak: gemm_s grid linearized, bid&7 = batch -> each batch's K+Q (4MB) lives
// in exactly one XCD L2 (r11 evidence: FETCH 74->40MB). Kernel body unchanged.
// gemm_o keeps the r9 phase schedule (BM=256xBN=128, 2-deep 96KB LDS, fine phases,
// ONE counted vmcnt(6)/K-tile, NT=32, bid&7 batch pin).
// ws (ushort elems): Pm[8*2048*2048] (Xb aliases head) | Wb[1536*512] | Qb | Kb
//   | Vtb[8*512*2048] | lde[16384 f32]  ~= 113.6 MB.

typedef __attribute__((ext_vector_type(8))) short short8;   // 8 x bf16
typedef __attribute__((ext_vector_type(4))) float f32x4;    // MFMA 16x16 acc

#define DEV __device__ __forceinline__
#define GLOBAL_AS __attribute__((address_space(1)))
#define LDS_AS __attribute__((address_space(3)))

static DEV ushort f2bs(float f) {  // fp32 -> bf16 bits, RNE
  union { float f; unsigned u; } x; x.f = f;
  unsigned r = (x.u + 0x7fffu + ((x.u >> 16) & 1u)) >> 16;
  return (ushort)r;
}

static DEV f32x4 mfma16(short8 a, short8 b, f32x4 c) {
  // C[m][n] += sum_k A[m][k]*B[n][k]
  return __builtin_amdgcn_mfma_f32_16x16x32_bf16(a, b, c, 0, 0, 0);
}

static DEV void async16(const void* g, void* l) {
  __builtin_amdgcn_global_load_lds((const GLOBAL_AS void*)g, (LDS_AS void*)l, 16, 0, 0);
}

// ---------------------------------------------------------------------------
// fp32->bf16 converts (weights, X) + lde zeroing, one kernel.
__global__ void convert_all(const float* __restrict__ wq, const float* __restrict__ wk,
                            const float* __restrict__ wv, const float* __restrict__ x,
                            ushort* __restrict__ wb, ushort* __restrict__ xb,
                            float* __restrict__ lde) {
  int i = blockIdx.x * 256 + threadIdx.x;
  if (i >= 2293760) {                       // lde tail: 4096 float4 groups
    int off = (i - 2293760) * 4;
    float4 z; z.x = 0.f; z.y = 0.f; z.z = 0.f; z.w = 0.f;
    *(float4*)(lde + off) = z;
    return;
  }
  const float* src;
  ushort* dst;
  if (i < 196608) {
    int which = i >> 16;
    int off = (i & 65535) * 4;
    src = ((which == 0) ? wq : (which == 1) ? wk : wv) + off;
    dst = wb + (size_t)which * 262144 + off;
  } else {
    int off = (i - 196608) * 4;
    src = x + off;
    dst = xb + off;
  }
  float4 v = *(const float4*)src;
  ushort4 o;
  o.x = f2bs(v.x); o.y = f2bs(v.y); o.z = f2bs(v.z); o.w = f2bs(v.w);
  *(ushort4*)dst = o;
}

// ---------------------------------------------------------------------------
// Shared K-loop (BK=64): stage A/B 128x64-bf16 tiles, swizzled, then 2 k-slices.
// As/Bs rows are 128B = 8 chunks of 16B; LDS chunk c holds global chunk c^(row&7).
#define KLOOP_STAGE(Aptr, lda, Bptr, ldb)                                      \
  do {                                                                         \
    _Pragma("unroll")                                                          \
    for (int t = 0; t < 8; t++) {                                              \
      int rowbase = (t & 3) * 32 + wave * 8;                                   \
      int r = rowbase + (lane >> 3);                                           \
      int gc = (lane & 7) ^ (r & 7);                                           \
      if (t < 4)                                                               \
        async16((Aptr) + (size_t)(rowblk * 128 + r) * (lda) + kb + gc * 8,     \
                &As[rowbase * 64]);                                            \
      else                                                                     \
        async16((Bptr) + (size_t)(colblk * 128 + r) * (ldb) + kb + gc * 8,     \
                &Bs[rowbase * 64]);                                            \
    }                                                                          \
  } while (0)

#define KLOOP_MFMA()                                                           \
  do {                                                                         \
    _Pragma("unroll")                                                          \
    for (int ks = 0; ks < 2; ks++) {                                           \
      short8 af[4], bfr[4];                                                    \
      _Pragma("unroll")                                                        \
      for (int t = 0; t < 4; t++) {                                            \
        int ra = wm * 64 + t * 16 + c16;                                       \
        int rb = wn * 64 + t * 16 + c16;                                       \
        af[t]  = *(const short8*)&As[ra * 64 + (((ks * 4 + quad) ^ (ra & 7)) * 8)]; \
        bfr[t] = *(const short8*)&Bs[rb * 64 + (((ks * 4 + quad) ^ (rb & 7)) * 8)]; \
      }                                                                        \
      _Pragma("unroll")                                                        \
      for (int mt = 0; mt < 4; mt++)                                           \
        _Pragma("unroll")                                                      \
        for (int nt = 0; nt < 4; nt++)                                         \
          acc[mt][nt] = mfma16(af[mt], bfr[nt], acc[mt][nt]);                  \
    }                                                                          \
  } while (0)

// ---------------------------------------------------------------------------
// Fused QKV GEMM: C[n][eg] = sum_d X[n][d]*W[eg][d] + bias, eg in [0,1536).
// eg<512 -> Q (scaled 1/sqrt(D)), <1024 -> K, else V^T [b][d][n].
__launch_bounds__(256, 4)
__global__ void qkv_gemm(const ushort* __restrict__ Xb, const ushort* __restrict__ Wb,
                         const float* __restrict__ bq, const float* __restrict__ bk,
                         const float* __restrict__ bv,
                         ushort* __restrict__ Qb, ushort* __restrict__ Kb,
                         ushort* __restrict__ Vtb) {
  const int rowblk = blockIdx.x;      // 0..127 (token rows)
  const int colblk = blockIdx.y;      // 0..11  (output cols / 128)
  const int z = colblk >> 2;          // 0 Q, 1 K, 2 V

  __shared__ ushort S[2 * 128 * 64];  // 32 KB: As | Bs (and epilogue transpose tile)
  ushort* As = S;
  ushort* Bs = S + 128 * 64;

  const int tid = threadIdx.x;
  const int wave = tid >> 6, lane = tid & 63, quad = lane >> 4, c16 = lane & 15;
  const int wm = wave & 1, wn = wave >> 1;

  f32x4 acc[4][4];
#pragma unroll
  for (int mt = 0; mt < 4; mt++)
#pragma unroll
    for (int nt = 0; nt < 4; nt++) acc[mt][nt] = (f32x4)0.0f;

  for (int kb = 0; kb < 512; kb += 64) {
    __syncthreads();
    KLOOP_STAGE(Xb, 512, Wb, 512);
    __syncthreads();
    KLOOP_MFMA();
  }

  const float* bias = (z == 0) ? bq : (z == 1) ? bk : bv;
  float bvals[4];
#pragma unroll
  for (int nt = 0; nt < 4; nt++) {
    int eg = colblk * 128 + wn * 64 + nt * 16 + c16;
    bvals[nt] = bias[eg & 511];
  }
  const float sc = (z == 0) ? 0.044194173824159216f : 1.0f;   // 1/sqrt(512) into Q

  const int row0 = rowblk * 128 + wm * 64;
  const int col0 = colblk * 128 + wn * 64;
  if (z < 2) {
    ushort* O = (z == 0) ? Qb : Kb;
#pragma unroll
    for (int mt = 0; mt < 4; mt++)
#pragma unroll
      for (int nt = 0; nt < 4; nt++) {
        int el = (col0 + nt * 16 + c16) & 511;
#pragma unroll
        for (int r = 0; r < 4; r++) {
          int n = row0 + mt * 16 + quad * 4 + r;
          O[(size_t)n * 512 + el] = f2bs((acc[mt][nt][r] + bvals[nt]) * sc);
        }
      }
  } else {
    // V^T: transpose via LDS (dead As+Bs), then 64-B sector-complete streaming stores.
    __syncthreads();                   // all waves done reading As/Bs
    ushort* T = S;                     // T[el 0..127][n 0..127], chunk-xor swizzled
#pragma unroll
    for (int nt = 0; nt < 4; nt++) {
      int ell = wn * 64 + nt * 16 + c16;       // local el
#pragma unroll
      for (int mt = 0; mt < 4; mt++) {
        int n0l = wm * 64 + mt * 16 + quad * 4; // local n (4 consecutive via r)
        ushort4 o;
        o.x = f2bs(acc[mt][nt][0] + bvals[nt]);
        o.y = f2bs(acc[mt][nt][1] + bvals[nt]);
        o.z = f2bs(acc[mt][nt][2] + bvals[nt]);
        o.w = f2bs(acc[mt][nt][3] + bvals[nt]);
        *(ushort4*)&T[ell * 128 + (((n0l >> 3) ^ (ell & 15)) << 3) + (n0l & 4)] = o;
      }
    }
    __syncthreads();
    const int c4 = tid & 3, er = tid >> 2;      // 4 lanes per row -> 64B runs
    const int bb = rowblk >> 4;
    const int nbase = (rowblk & 15) * 128;
    const int elbase = (colblk & 3) * 128;
#pragma unroll
    for (int part = 0; part < 2; part++) {
      int ell = part * 64 + er;
      size_t ge = ((size_t)bb * 512 + elbase + ell) * 2048;
#pragma unroll
      for (int j2 = 0; j2 < 4; j2++) {
        int n0 = j2 * 32 + c4 * 8;              // ushort units within the 128-n tile
        short8 v = *(short8*)&T[ell * 128 + (((n0 >> 3) ^ (ell & 15)) << 3)];
        *(short8*)(Vtb + ge + nbase + n0) = v;
      }
    }
  }
}

// ---------------------------------------------------------------------------
// gemm_s: per batch, C[m=key][n=query] = K.Q^T (Q pre-scaled).  r6 body, r13 grid:
// 2048 linear blocks, b = bid&7 (XCD pin: batch's K+Q = 4MB = one L2),
// rowblk = (bid>>3)&15 (key tile), colblk = bid>>7 (query tile).
__launch_bounds__(256, 4)
__global__ void gemm_s(const ushort* __restrict__ Kb, const ushort* __restrict__ Qb,
                       const int* __restrict__ mask, ushort* __restrict__ Pm,
                       float* __restrict__ l) {
  const int bid = blockIdx.x;
  const int b = bid & 7;
  const int rowblk = (bid >> 3) & 15;   // key tile
  const int colblk = bid >> 7;          // query tile
  const ushort* A  = Kb + (size_t)b * 2048 * 512;
  const ushort* Bq = Qb + (size_t)b * 2048 * 512;

  __shared__ ushort S[2 * 128 * 64];  // 32 KB
  ushort* As = S;
  ushort* Bs = S + 128 * 64;

  const int tid = threadIdx.x;
  const int wave = tid >> 6, lane = tid & 63, quad = lane >> 4, c16 = lane & 15;
  const int wm = wave & 1, wn = wave >> 1;

  f32x4 acc[4][4];
#pragma unroll
  for (int mt = 0; mt < 4; mt++)
#pragma unroll
    for (int nt = 0; nt < 4; nt++) acc[mt][nt] = (f32x4)0.0f;

  for (int kb = 0; kb < 512; kb += 64) {
    __syncthreads();
    KLOOP_STAGE(A, 512, Bq, 512);
    __syncthreads();
    KLOOP_MFMA();
  }

  const int row0 = rowblk * 128 + wm * 64;   // key base (global in batch)
  const int col0 = colblk * 128 + wn * 64;   // query base
  float lpart[4] = {0.0f, 0.0f, 0.0f, 0.0f};

  __syncthreads();                 // all waves done reading As/Bs; reuse S
  ushort* T = S;                   // T[q 0..127][key 0..127], chunk-xor swizzled
#pragma unroll
  for (int mt = 0; mt < 4; mt++) {
    int key0 = row0 + mt * 16 + quad * 4;       // global key (for mask)
    int k0l  = wm * 64 + mt * 16 + quad * 4;    // local key
    int4 mv = *(const int4*)&mask[b * 2048 + key0];
    float mf0 = mv.x ? 1.0f : 0.0f, mf1 = mv.y ? 1.0f : 0.0f;
    float mf2 = mv.z ? 1.0f : 0.0f, mf3 = mv.w ? 1.0f : 0.0f;
#pragma unroll
    for (int nt = 0; nt < 4; nt++) {
      int ql = wn * 64 + nt * 16 + c16;         // local query
      float p0 = __expf(acc[mt][nt][0]) * mf0;
      float p1 = __expf(acc[mt][nt][1]) * mf1;
      float p2 = __expf(acc[mt][nt][2]) * mf2;
      float p3 = __expf(acc[mt][nt][3]) * mf3;
      ushort4 o;
      o.x = f2bs(p0); o.y = f2bs(p1); o.z = f2bs(p2); o.w = f2bs(p3);
      *(ushort4*)&T[ql * 128 + (((k0l >> 3) ^ (ql & 15)) << 3) + (k0l & 4)] = o;
      lpart[nt] += p0 + p1 + p2 + p3;
    }
  }
#pragma unroll
  for (int nt = 0; nt < 4; nt++) {
    float v = lpart[nt];
    v += __shfl_xor(v, 16, 64);
    v += __shfl_xor(v, 32, 64);
    if (quad == 0) atomicAdd(&l[b * 2048 + col0 + nt * 16 + c16], v);
  }
  __syncthreads();
  {
    const int c4 = tid & 3, er = tid >> 2;      // 4 lanes per q-row -> 64B runs
#pragma unroll
    for (int part = 0; part < 2; part++) {
      int ql = part * 64 + er;
      size_t gq = ((size_t)b * 2048 + colblk * 128 + ql) * 2048;
#pragma unroll
      for (int j2 = 0; j2 < 4; j2++) {
        int n0 = j2 * 32 + c4 * 8;              // ushort units within 128-key tile
        short8 v = *(short8*)&T[ql * 128 + (((n0 >> 3) ^ (ql & 15)) << 3)];
        *(short8*)(Pm + gq + rowblk * 128 + n0) = v;
      }
    }
  }
}

// ===========================================================================
// gemm_o phase machinery (r9-proven): BM=256 x BN=128, 8 waves, 96KB 2-deep LDS,
// per-tile fine phases + ONE counted vmcnt(6) per K-tile.
#define PH_ST_A(pp, kt, rd)                                                    \
  do {                                                                         \
    int rowbase_ = (rd) * 64 + wave * 8;                                       \
    int r_ = rowbase_ + (lane >> 3);                                           \
    int gc_ = (lane & 7) ^ (r_ & 7);                                           \
    async16(gA + (size_t)(arow0 + r_) * glda + (kt) * 64 + gc_ * 8,            \
            SdA + (pp) * 16384 + rowbase_ * 64);                               \
  } while (0)

#define PH_ST_B(pp, kt, rd)                                                    \
  do {                                                                         \
    int rowbase_ = (rd) * 64 + wave * 8;                                       \
    int r_ = rowbase_ + (lane >> 3);                                           \
    int gc_ = (lane & 7) ^ (r_ & 7);                                           \
    async16(gB + (size_t)(brow0 + r_) * gldb + (kt) * 64 + gc_ * 8,            \
            SdB + (pp) * 8192 + rowbase_ * 64);                                \
  } while (0)

#define PH_READ(pp, ks, afx, bfx)                                              \
  do {                                                                         \
    const ushort* Ap_ = SdA + (pp) * 16384;                                    \
    const ushort* Bp_ = SdB + (pp) * 8192;                                     \
    _Pragma("unroll")                                                          \
    for (int mf = 0; mf < 4; mf++) {                                           \
      int ra = wm * 64 + mf * 16 + c16;                                        \
      afx[mf] = *(const short8*)&Ap_[ra * 64 + ((((ks)*4 + quad) ^ (ra & 7)) * 8)]; \
    }                                                                          \
    _Pragma("unroll")                                                          \
    for (int nf = 0; nf < 4; nf++) {                                           \
      int rb = wn * 64 + nf * 16 + c16;                                        \
      bfx[nf] = *(const short8*)&Bp_[rb * 64 + ((((ks)*4 + quad) ^ (rb & 7)) * 8)]; \
    }                                                                          \
  } while (0)

#define PH_MFMA(afx, bfx, h)                                                   \
  do {                                                                         \
    __builtin_amdgcn_s_setprio(1);                                             \
    _Pragma("unroll")                                                          \
    for (int mf = (h) * 2; mf < (h) * 2 + 2; mf++)                             \
      _Pragma("unroll")                                                        \
      for (int nf = 0; nf < 4; nf++)                                           \
        acc[mf][nf] = mfma16(afx[mf], bfx[nf], acc[mf][nf]);                   \
    __builtin_amdgcn_s_setprio(0);                                             \
  } while (0)

#define PH_TILE(pp, kt, dostage)                                               \
  do {                                                                         \
    PH_READ(pp, 0, af0, bf0);                                                  \
    __builtin_amdgcn_s_barrier();                                              \
    asm volatile("s_waitcnt lgkmcnt(0)" ::: "memory");                         \
    __builtin_amdgcn_sched_barrier(0);                                         \
    PH_MFMA(af0, bf0, 0);                                                      \
    __builtin_amdgcn_s_barrier();                                              \
    PH_READ(pp, 1, af1, bf1);                                                  \
    __builtin_amdgcn_s_barrier();                                              \
    asm volatile("s_waitcnt lgkmcnt(0)" ::: "memory");                         \
    __builtin_amdgcn_sched_barrier(0);                                         \
    PH_MFMA(af0, bf0, 1);                                                      \
    __builtin_amdgcn_s_barrier();   /* all waves' buf-pp reads retired */      \
    if (dostage) { PH_ST_A(pp, (kt) + 2, 0); PH_ST_A(pp, (kt) + 2, 1);         \
                   PH_ST_A(pp, (kt) + 2, 2); }                                 \
    PH_MFMA(af1, bf1, 0);                                                      \
    __builtin_amdgcn_s_barrier();                                              \
    if (dostage) { PH_ST_A(pp, (kt) + 2, 3); PH_ST_B(pp, (kt) + 2, 0);         \
                   PH_ST_B(pp, (kt) + 2, 1); }                                 \
    PH_MFMA(af1, bf1, 1);                                                      \
    if (dostage) { asm volatile("s_waitcnt vmcnt(6)" ::: "memory"); }          \
    else         { asm volatile("s_waitcnt vmcnt(0)" ::: "memory"); }          \
    __builtin_amdgcn_sched_barrier(0);                                         \
    __builtin_amdgcn_s_barrier();   /* next tile resident for all waves */     \
  } while (0)

#define PH_PROLOGUE()                                                          \
  do {                                                                         \
    PH_ST_A(0, 0, 0); PH_ST_A(0, 0, 1); PH_ST_A(0, 0, 2); PH_ST_A(0, 0, 3);    \
    PH_ST_B(0, 0, 0); PH_ST_B(0, 0, 1);                                        \
    PH_ST_A(1, 1, 0); PH_ST_A(1, 1, 1); PH_ST_A(1, 1, 2); PH_ST_A(1, 1, 3);    \
    PH_ST_B(1, 1, 0); PH_ST_B(1, 1, 1);                                        \
    asm volatile("s_waitcnt vmcnt(6)" ::: "memory");                           \
    __builtin_amdgcn_sched_barrier(0);                                         \
    __builtin_amdgcn_s_barrier();                                              \
  } while (0)

// gemm_o, phase-scheduled (r9): per batch C[m=query][n=d] = P . V^T; /l, fp32 out.
__launch_bounds__(512, 2)
__global__ void gemm_o(const ushort* __restrict__ Pm, const ushort* __restrict__ Vtb,
                       const float* __restrict__ l, float* __restrict__ out) {
  const int bid = blockIdx.x;
  const int b = bid & 7;             // batch -> XCD pin
  const int rowblk = (bid >> 3) & 7; // query tile 0..7 (256 rows)
  const int colblk = bid >> 6;       // d tile 0..3 (128 cols)

  extern __shared__ ushort Sd[];     // 96 KB
  ushort* SdA = Sd;
  ushort* SdB = Sd + 32768;

  const int tid = threadIdx.x;
  const int wave = tid >> 6, lane = tid & 63, quad = lane >> 4, c16 = lane & 15;
  const int wm = wave >> 1, wn = wave & 1;   // 4M x 2N; per-wave 64q x 64d

  const ushort* gA = Pm + (size_t)b * 2048 * 2048;  const int glda = 2048;
  const int arow0 = rowblk * 256;
  const ushort* gB = Vtb + (size_t)b * 512 * 2048;  const int gldb = 2048;
  const int brow0 = colblk * 128;

  f32x4 acc[4][4];
#pragma unroll
  for (int mf = 0; mf < 4; mf++)
#pragma unroll
    for (int nf = 0; nf < 4; nf++) acc[mf][nf] = (f32x4)0.0f;

  PH_PROLOGUE();
  short8 af0[4], bf0[4], af1[4], bf1[4];
  for (int i = 0; i < 16; i++) {
    const int ds = (i < 15);
    PH_TILE(0, 2 * i, ds);
    PH_TILE(1, 2 * i + 1, ds);
  }

  // Epilogue: /l, fp32 out.
  const int row0 = rowblk * 256 + wm * 64;   // query
  const int col0 = colblk * 128 + wn * 64;   // d
  float linv[4][4];
#pragma unroll
  for (int mf = 0; mf < 4; mf++)
#pragma unroll
    for (int r = 0; r < 4; r++)
      linv[mf][r] = 1.0f / l[b * 2048 + row0 + mf * 16 + quad * 4 + r];
#pragma unroll
  for (int mf = 0; mf < 4; mf++)
#pragma unroll
    for (int nf = 0; nf < 4; nf++) {
      int col = col0 + nf * 16 + c16;
#pragma unroll
      for (int r = 0; r < 4; r++) {
        int row = row0 + mf * 16 + quad * 4 + r;
        out[((size_t)b * 2048 + row) * 512 + col] = acc[mf][nf][r] * linv[mf][r];
      }
    }
}

// ---------------------------------------------------------------------------
extern "C" void kernel_launch(void* const* d_in, const int* in_sizes, int n_in,
                              void* d_out, int out_size, void* d_ws, size_t ws_size,
                              hipStream_t stream) {
  (void)in_sizes; (void)n_in; (void)out_size; (void)ws_size;
  const float* X    = (const float*)d_in[0];
  const int*   mask = (const int*)d_in[1];
  const float* Wk   = (const float*)d_in[2];
  const float* bk   = (const float*)d_in[3];
  const float* Wq   = (const float*)d_in[4];
  const float* bq   = (const float*)d_in[5];
  const float* Wv   = (const float*)d_in[6];
  const float* bv   = (const float*)d_in[7];
  float* out = (float*)d_out;

  ushort* ws  = (ushort*)d_ws;
  ushort* Pm  = ws;                             // [8][2048][2048] bf16 (64 MB)
  ushort* Xb  = ws;                             // [16384][512] aliases Pm (dead after qkv)
  ushort* Wb  = ws + (size_t)33554432;          // [1536][512]  rows = [Wq;Wk;Wv]
  ushort* Qb  = Wb + (size_t)786432;            // [16384][512] pre-scaled
  ushort* Kb  = Qb + (size_t)8388608;           // [16384][512]
  ushort* Vtb = Kb + (size_t)8388608;           // [8][512][2048]
  float*  lde = (float*)(Vtb + (size_t)8388608);// [16384] softmax denominators

  convert_all<<<8976, 256, 0, stream>>>(Wq, Wk, Wv, X, Wb, Xb, lde);
  qkv_gemm<<<dim3(128, 12), 256, 0, stream>>>(Xb, Wb, bq, bk, bv, Qb, Kb, Vtb);
  gemm_s<<<2048, 256, 0, stream>>>(Kb, Qb, mask, Pm, lde);
  gemm_o<<<256, 512, 98304, stream>>>(Pm, Vtb, lde, out);
}